// Round 2
// baseline (263.472 us; speedup 1.0000x reference)
//
#include <hip/hip_runtime.h>
#include <hip/hip_bf16.h>

// Stage 1: precompute per-element "full" trapezoid weights into d_ws, and zero d_out.
//   w_full[k] = 0.5*(x[k]-x[k-1])*[k>=1] + 0.5*(x[k+1]-x[k])*[k<=n-2]
// Row-dependent masking then reduces to a single boundary correction at k=idx.
__global__ void weight_kernel(const float* __restrict__ x,
                              float* __restrict__ w,
                              float* __restrict__ out, int n) {
    int k = blockIdx.x * blockDim.x + threadIdx.x;
    if (k == 0) out[0] = 0.0f;   // replaces a separate memset dispatch
    if (k < n) {
        float left  = (k >= 1)     ? 0.5f * (x[k] - x[k - 1]) : 0.0f;
        float right = (k <= n - 2) ? 0.5f * (x[k + 1] - x[k]) : 0.0f;
        w[k] = left + right;
    }
}

// Stage 2: one block per row.
//   row_sum = sum_{k<=idx} w_full[k]*(p[k]-t[k])  -  0.5*(x[idx+1]-x[idx])*(p[idx]-t[idx]) if idx<n-1
// Only 3 VMEM instructions per float4 quad (w is 32 KB, L1/L2-resident).
// Elements with k > idx are never loaded (halves HBM traffic on average).
__global__ __launch_bounds__(256) void strain_loss_kernel(
    const float* __restrict__ y_pred,
    const float* __restrict__ y_true,
    const float* __restrict__ x,
    const float* __restrict__ w,
    const int*   __restrict__ fidx,
    float* __restrict__ out,
    int n, float inv_b)
{
    const int row = blockIdx.x;
    const int tid = threadIdx.x;

    int idx = fidx[row];
    idx = idx < 0 ? 0 : (idx > n - 1 ? n - 1 : idx);

    const float* p = y_pred + (long long)row * n;
    const float* t = y_true + (long long)row * n;

    float acc = 0.0f;
    for (int k0 = tid * 4; k0 <= idx; k0 += 256 * 4) {
        float4 pv = *(const float4*)(p + k0);
        float4 tv = *(const float4*)(t + k0);
        float4 wv = *(const float4*)(w + k0);
        int rem = idx - k0;                     // >= 0 by loop condition
        acc += wv.x * (pv.x - tv.x);            // k0 <= idx always
        acc += (rem >= 1) ? wv.y * (pv.y - tv.y) : 0.0f;
        acc += (rem >= 2) ? wv.z * (pv.z - tv.z) : 0.0f;
        acc += (rem >= 3) ? wv.w * (pv.w - tv.w) : 0.0f;
    }

    // Boundary correction: w_full over-counts the right half-segment at k=idx.
    if (tid == 0 && idx < n - 1) {
        acc -= 0.5f * (x[idx + 1] - x[idx]) * (p[idx] - t[idx]);
    }

    // Wave (64-lane) shuffle reduction, then cross-wave via LDS.
    #pragma unroll
    for (int off = 32; off > 0; off >>= 1)
        acc += __shfl_down(acc, off, 64);

    __shared__ float wave_sums[4];
    const int wave = tid >> 6;
    if ((tid & 63) == 0) wave_sums[wave] = acc;
    __syncthreads();

    if (tid == 0) {
        float s = wave_sums[0] + wave_sums[1] + wave_sums[2] + wave_sums[3];
        atomicAdd(out, s * s * inv_b);   // mean of squared errors
    }
}

extern "C" void kernel_launch(void* const* d_in, const int* in_sizes, int n_in,
                              void* d_out, int out_size, void* d_ws, size_t ws_size,
                              hipStream_t stream) {
    const float* y_pred = (const float*)d_in[0];
    const float* y_true = (const float*)d_in[1];
    const float* x      = (const float*)d_in[2];
    const int*   fidx   = (const int*)d_in[3];
    float* out = (float*)d_out;
    float* w   = (float*)d_ws;           // n floats = 32 KB scratch

    const int n = in_sizes[2];   // 8192
    const int b = in_sizes[3];   // 4096

    weight_kernel<<<dim3((n + 255) / 256), dim3(256), 0, stream>>>(x, w, out, n);
    strain_loss_kernel<<<dim3(b), dim3(256), 0, stream>>>(
        y_pred, y_true, x, w, fidx, out, n, 1.0f / (float)b);
}